// Round 5
// baseline (34.897 us; speedup 1.0000x reference)
//
#include <hip/hip_runtime.h>

#define HID 64
#define VOC 64
#define NSLOT 8
#define NB 256
#define SEQL 2048
#define NT 512            // 8 waves
#define NW (NT / 64)
#define EPAD 65           // embed/z LDS pitch: bank (v+i)%32, conflict-free
#define FPAD 129          // ff1/h  LDS pitch: bank (v+j)%32, conflict-free

// ---------------------------------------------------------------------------
// Single fused kernel, 256 blocks x 512 threads. Each block redundantly
// computes the 64-row vocab table (FFN+LN+score) with lane=vocab-row and
// SGPR-broadcast weights, then processes its own batch row: register-held
// seq count-passes down the score order -> top-8 multiset -> attention ->
// entropy gate -> logits. Entropy mean via one atomicAdd per block into a
// scalar zeroed by a preceding 4-byte memset node.
// ---------------------------------------------------------------------------
__global__ __launch_bounds__(NT) void fused_kernel(
    const int* __restrict__ seq,
    const float* __restrict__ embed, const float* __restrict__ w1, const float* __restrict__ b1,
    const float* __restrict__ w2, const float* __restrict__ b2,
    const float* __restrict__ ln_g, const float* __restrict__ ln_b,
    const float* __restrict__ gate_w, const float* __restrict__ gate_b,
    const float* __restrict__ q_w, const float* __restrict__ q_b,
    const float* __restrict__ out_w, const float* __restrict__ out_b,
    float* __restrict__ out, float* __restrict__ ent_out)
{
    __shared__ float semb[VOC * EPAD];   // embed rows; z in place after FFN2
    __shared__ float sff[VOC * FPAD];    // ff1 rows; h in place after LN
    __shared__ float sscore[VOC];
    __shared__ int   sorder[VOC];
    __shared__ float sqv[HID];
    __shared__ float sctx[HID];
    __shared__ int   svids[NSLOT];
    __shared__ float sla[NSLOT];
    __shared__ float seff[NSLOT];
    __shared__ int   scw[NW];
    __shared__ int   s_u, s_rem, s_nv;
    __shared__ int   shvlast;

    const int t = threadIdx.x;
    const int b = blockIdx.x;
    const int lane = t & 63;
    const int wave = t >> 6;

    // Issue this block's seq row load first; consumed ~3 us later.
    const int4 a = ((const int4*)(seq + (size_t)b * SEQL))[t];

    // Stage embed into LDS (coalesced scalar loads).
    for (int p = t; p < VOC * HID; p += NT)
        semb[(p >> 6) * EPAD + (p & 63)] = embed[p];
    if (t == 0) { s_rem = NSLOT; s_nv = 0; }
    if (t == NT - 1) shvlast = a.w;      // seq[b][2047]
    __syncthreads();

    // ---- FFN1: lane = v, wave handles j in [wave*16, wave*16+16) ----------
    // ff1[v][j] = relu(b1[j] + sum_i e[v][i] * w1[i][j]); weights via SGPR.
    {
        const int jb = __builtin_amdgcn_readfirstlane(wave * 16);
        float acc[16];
#pragma unroll
        for (int jj = 0; jj < 16; ++jj) acc[jj] = b1[jb + jj];
#pragma unroll 4
        for (int i = 0; i < HID; ++i) {
            const float ev = semb[lane * EPAD + i];
            const float* wr = w1 + i * 2 * HID + jb;   // uniform -> s_load
#pragma unroll
            for (int jj = 0; jj < 16; ++jj)
                acc[jj] = fmaf(ev, wr[jj], acc[jj]);
        }
#pragma unroll
        for (int jj = 0; jj < 16; ++jj)
            sff[lane * FPAD + jb + jj] = fmaxf(acc[jj], 0.0f);
    }
    __syncthreads();

    // ---- FFN2 + residual: lane = v, wave handles i in [wave*8, wave*8+8) --
    {
        const int ib = __builtin_amdgcn_readfirstlane(wave * 8);
        float zacc[8];
#pragma unroll
        for (int ii = 0; ii < 8; ++ii) zacc[ii] = b2[ib + ii];
#pragma unroll 4
        for (int j = 0; j < 2 * HID; ++j) {
            const float fv = sff[lane * FPAD + j];
            const float* wr = w2 + j * HID + ib;       // uniform -> s_load
#pragma unroll
            for (int ii = 0; ii < 8; ++ii)
                zacc[ii] = fmaf(fv, wr[ii], zacc[ii]);
        }
#pragma unroll
        for (int ii = 0; ii < 8; ++ii)
            semb[lane * EPAD + ib + ii] += zacc[ii];   // z = e + ffn
    }
    __syncthreads();

    // ---- LayerNorm + gate score: wave handles rows [wave*8, wave*8+8) -----
    {
        const float lng = ln_g[lane], lnb = ln_b[lane], gw = gate_w[lane];
        const int rbase = wave * 8;
        for (int rr = 0; rr < 8; ++rr) {
            const int r = rbase + rr;
            const float z = semb[r * EPAD + lane];
            float s = z;
#pragma unroll
            for (int m = 32; m; m >>= 1) s += __shfl_xor(s, m);
            const float mu = s * (1.0f / HID);
            const float d = z - mu;
            float vs = d * d;
#pragma unroll
            for (int m = 32; m; m >>= 1) vs += __shfl_xor(vs, m);
            const float inv = 1.0f / sqrtf(vs * (1.0f / HID) + 1e-5f);
            const float h = d * inv * lng + lnb;
            sff[r * FPAD + lane] = h;                  // h overwrites ff1 row
            float sc = h * gw;
#pragma unroll
            for (int m = 32; m; m >>= 1) sc += __shfl_xor(sc, m);
            if (lane == 0) sscore[r] = sc + gate_b[0];
        }
    }
    __syncthreads();

    // ---- rank ids by score desc (tie -> lower id) -------------------------
    if (t < VOC) {
        const float sv = sscore[t];
        int r = 0;
        for (int u = 0; u < VOC; ++u) {
            const float su = sscore[u];
            if (su > sv || (su == sv && u < t)) ++r;
        }
        sorder[r] = t;
    }
    __syncthreads();

    // ---- greedy top-8 multiset via register count-passes (exp. 1 pass) ----
    for (int pos = 0; pos < VOC; ++pos) {
        if (t == 0) s_u = sorder[pos];
        __syncthreads();
        const int u = s_u;
        int c = (a.x == u) + (a.y == u) + (a.z == u) + (a.w == u);
#pragma unroll
        for (int m = 32; m; m >>= 1) c += __shfl_xor(c, m);
        if (lane == 0) scw[wave] = c;
        __syncthreads();
        if (t == 0) {
            int tot = 0;
            for (int w = 0; w < NW; ++w) tot += scw[w];
            int take = tot < s_rem ? tot : s_rem;
            for (int k = 0; k < take; ++k) svids[s_nv++] = u;
            s_rem -= take;
        }
        __syncthreads();
        if (s_rem == 0) break;
    }

    // ---- q row of last token: q[t] = q_b[t] + sum_k h[vlast][k] q_w[k][t] -
    const int vlast = shvlast;
    if (t < HID) {
        float qa = q_b[t];
        for (int k = 0; k < HID; ++k)
            qa = fmaf(sff[vlast * FPAD + k], q_w[k * HID + t], qa);
        sqv[t] = qa;
    }
    __syncthreads();

    // ---- attention logits: 8 lanes per slot, 3-step shfl reduce -----------
    if (t < VOC) {
        const int k = t >> 3, e = t & 7;
        const float* hr = &sff[svids[k] * FPAD];
        float p = 0.0f;
#pragma unroll
        for (int m = 0; m < 8; ++m)
            p = fmaf(hr[e + 8 * m], sqv[e + 8 * m], p);
        p += __shfl_xor(p, 1);
        p += __shfl_xor(p, 2);
        p += __shfl_xor(p, 4);
        if (e == 0) sla[k] = p * 0.125f;               // 1/sqrt(64)
    }
    __syncthreads();

    // ---- softmax + entropy gate; one atomicAdd for batch-mean entropy -----
    if (t == 0) {
        float m = -1e30f;
        for (int k = 0; k < NSLOT; ++k) m = fmaxf(m, sla[k]);
        float e[NSLOT], s = 0.0f;
        for (int k = 0; k < NSLOT; ++k) { e[k] = expf(sla[k] - m); s += e[k]; }
        const float invs = 1.0f / s;
        float ent = 0.0f;
        for (int k = 0; k < NSLOT; ++k) {
            const float av = e[k] * invs;
            ent -= av * logf(av + 1e-9f);
        }
        const float high = (ent > 1.5f) ? 1.0f : 0.0f;
        for (int k = 0; k < NSLOT; ++k)
            seff[k] = (1.0f - high) * (e[k] * invs) + high * (1.0f / NSLOT);
        atomicAdd(ent_out, ent * (1.0f / NB));
    }
    __syncthreads();

    // ---- ctx then logits --------------------------------------------------
    if (t < HID) {
        float cx = 0.0f;
#pragma unroll
        for (int k = 0; k < NSLOT; ++k)
            cx = fmaf(seff[k], sff[svids[k] * FPAD + t], cx);
        sctx[t] = cx;
    }
    __syncthreads();
    if (t < VOC) {
        float o = out_b[t];
        for (int i = 0; i < HID; ++i)
            o = fmaf(sctx[i], out_w[i * VOC + t], o);
        out[(size_t)b * VOC + t] = o;
    }
}

extern "C" void kernel_launch(void* const* d_in, const int* in_sizes, int n_in,
                              void* d_out, int out_size, void* d_ws, size_t ws_size,
                              hipStream_t stream) {
    const int*   seq    = (const int*)  d_in[0];
    const float* embed  = (const float*)d_in[1];
    const float* w1     = (const float*)d_in[2];
    const float* b1     = (const float*)d_in[3];
    const float* w2     = (const float*)d_in[4];
    const float* b2     = (const float*)d_in[5];
    const float* ln_g   = (const float*)d_in[6];
    const float* ln_b   = (const float*)d_in[7];
    const float* gate_w = (const float*)d_in[8];
    const float* gate_b = (const float*)d_in[9];
    const float* q_w    = (const float*)d_in[10];
    const float* q_b    = (const float*)d_in[11];
    const float* out_w  = (const float*)d_in[12];
    const float* out_b  = (const float*)d_in[13];
    float* out = (float*)d_out;
    float* ent_out = out + (size_t)NB * VOC;

    hipMemsetAsync(ent_out, 0, sizeof(float), stream);
    fused_kernel<<<NB, NT, 0, stream>>>(seq, embed, w1, b1, w2, b2, ln_g, ln_b,
                                        gate_w, gate_b, q_w, q_b, out_w, out_b,
                                        out, ent_out);
}

// Round 6
// 32.158 us; speedup vs baseline: 1.0852x; 1.0852x over previous
//
#include <hip/hip_runtime.h>

#define HID 64
#define VOC 64
#define NSLOT 8
#define NB 256
#define SEQL 2048
#define NT 512            // 8 waves
#define NW (NT / 64)
#define EPAD 65           // embed/z LDS pitch: bank (v+i)%32, conflict-free
#define FPAD 129          // ff1/h  LDS pitch: bank (v+j)%32, conflict-free
#define MAGIC 0x5EED0001

// ---------------------------------------------------------------------------
// Single kernel, NB+1 blocks x 512 threads, ZERO auxiliary nodes.
//  blocks 0..255 : redundant per-block vocab table (FFN+LN+score) with
//                  float4 weight loads (4x fewer VMEM instructions than r5),
//                  then own-row top-8 -> attention -> entropy gate -> logits.
//                  Tail: atomic-store entw[b] + release-store magic flag.
//  block 256     : spinner; polls the 256 flags with atomic LOADS (no RMW),
//                  deterministic tree-reduce -> entropy mean, resets flags
//                  to 0 so the next graph replay starts clean. Poison-safe:
//                  0xAAAAAAAA != MAGIC, entw written before flag released.
// ---------------------------------------------------------------------------
__global__ __launch_bounds__(NT) void fused_kernel(
    const int* __restrict__ seq,
    const float* __restrict__ embed, const float* __restrict__ w1, const float* __restrict__ b1,
    const float* __restrict__ w2, const float* __restrict__ b2,
    const float* __restrict__ ln_g, const float* __restrict__ ln_b,
    const float* __restrict__ gate_w, const float* __restrict__ gate_b,
    const float* __restrict__ q_w, const float* __restrict__ q_b,
    const float* __restrict__ out_w, const float* __restrict__ out_b,
    float* __restrict__ out, float* __restrict__ entw, int* __restrict__ flags)
{
    const int t = threadIdx.x;
    const int b = blockIdx.x;
    const int lane = t & 63;
    const int wave = t >> 6;

    __shared__ float semb[VOC * EPAD];   // embed rows; z in place after FFN2
    __shared__ float sff[VOC * FPAD];    // ff1 rows; h in place after LN
    __shared__ float sscore[VOC];
    __shared__ int   sorder[VOC];
    __shared__ float sqv[HID];
    __shared__ float sctx[HID];
    __shared__ int   svids[NSLOT];
    __shared__ float sla[NSLOT];
    __shared__ float seff[NSLOT];
    __shared__ int   scw[NW];
    __shared__ int   s_u, s_rem, s_nv;
    __shared__ int   shvlast;
    __shared__ float sred[NB];

    // ---- spinner block: gather entropies, reduce, write mean, reset flags -
    if (b == NB) {
        if (t < NB) {
            while (__hip_atomic_load(&flags[t], __ATOMIC_ACQUIRE,
                                     __HIP_MEMORY_SCOPE_AGENT) != MAGIC)
                __builtin_amdgcn_s_sleep(8);
            const float v = __hip_atomic_load(&entw[t], __ATOMIC_RELAXED,
                                              __HIP_MEMORY_SCOPE_AGENT);
            __hip_atomic_store(&flags[t], 0, __ATOMIC_RELAXED,
                               __HIP_MEMORY_SCOPE_AGENT);
            sred[t] = v;
        }
        __syncthreads();
        for (int s = NB / 2; s > 0; s >>= 1) {
            if (t < s) sred[t] += sred[t + s];
            __syncthreads();
        }
        if (t == 0) out[(size_t)NB * VOC] = sred[0] * (1.0f / NB);
        return;
    }

    // ---- producer path ----------------------------------------------------
    // Issue this block's seq row load first; consumed much later.
    const int4 a = ((const int4*)(seq + (size_t)b * SEQL))[t];

    // Stage embed into LDS (float4 global loads, scalar LDS writes: EPAD odd).
    for (int p = t; p < VOC * HID / 4; p += NT) {
        const float4 v = ((const float4*)embed)[p];
        const int r = (p * 4) >> 6, c = (p * 4) & 63;
        float* dst = &semb[r * EPAD + c];
        dst[0] = v.x; dst[1] = v.y; dst[2] = v.z; dst[3] = v.w;
    }
    if (t == 0) { s_rem = NSLOT; s_nv = 0; }
    if (t == NT - 1) shvlast = a.w;      // seq[b][2047]
    __syncthreads();

    // ---- FFN1: lane = v, wave handles j in [wave*16, wave*16+16) ----------
    {
        const int jb = __builtin_amdgcn_readfirstlane(wave * 16);
        float acc[16];
#pragma unroll
        for (int jj = 0; jj < 16; ++jj) acc[jj] = b1[jb + jj];
#pragma unroll 4
        for (int i = 0; i < HID; ++i) {
            const float ev = semb[lane * EPAD + i];
            const float4* w4 = (const float4*)(w1 + i * 2 * HID + jb);
#pragma unroll
            for (int jq = 0; jq < 4; ++jq) {
                const float4 wv = w4[jq];
                acc[4 * jq + 0] = fmaf(ev, wv.x, acc[4 * jq + 0]);
                acc[4 * jq + 1] = fmaf(ev, wv.y, acc[4 * jq + 1]);
                acc[4 * jq + 2] = fmaf(ev, wv.z, acc[4 * jq + 2]);
                acc[4 * jq + 3] = fmaf(ev, wv.w, acc[4 * jq + 3]);
            }
        }
#pragma unroll
        for (int jj = 0; jj < 16; ++jj)
            sff[lane * FPAD + jb + jj] = fmaxf(acc[jj], 0.0f);
    }
    __syncthreads();

    // ---- FFN2 + residual: lane = v, wave handles i in [wave*8, wave*8+8) --
    {
        const int ib = __builtin_amdgcn_readfirstlane(wave * 8);
        float zacc[8];
#pragma unroll
        for (int ii = 0; ii < 8; ++ii) zacc[ii] = b2[ib + ii];
#pragma unroll 4
        for (int j = 0; j < 2 * HID; ++j) {
            const float fv = sff[lane * FPAD + j];
            const float4* w4 = (const float4*)(w2 + j * HID + ib);
            const float4 wv0 = w4[0], wv1 = w4[1];
            zacc[0] = fmaf(fv, wv0.x, zacc[0]);
            zacc[1] = fmaf(fv, wv0.y, zacc[1]);
            zacc[2] = fmaf(fv, wv0.z, zacc[2]);
            zacc[3] = fmaf(fv, wv0.w, zacc[3]);
            zacc[4] = fmaf(fv, wv1.x, zacc[4]);
            zacc[5] = fmaf(fv, wv1.y, zacc[5]);
            zacc[6] = fmaf(fv, wv1.z, zacc[6]);
            zacc[7] = fmaf(fv, wv1.w, zacc[7]);
        }
#pragma unroll
        for (int ii = 0; ii < 8; ++ii)
            semb[lane * EPAD + ib + ii] += zacc[ii];   // z = e + ffn
    }
    __syncthreads();

    // ---- LayerNorm + gate score: wave handles rows [wave*8, wave*8+8) -----
    {
        const float lng = ln_g[lane], lnb = ln_b[lane], gw = gate_w[lane];
        const int rbase = wave * 8;
        for (int rr = 0; rr < 8; ++rr) {
            const int r = rbase + rr;
            const float z = semb[r * EPAD + lane];
            float s = z;
#pragma unroll
            for (int m = 32; m; m >>= 1) s += __shfl_xor(s, m);
            const float mu = s * (1.0f / HID);
            const float d = z - mu;
            float vs = d * d;
#pragma unroll
            for (int m = 32; m; m >>= 1) vs += __shfl_xor(vs, m);
            const float inv = 1.0f / sqrtf(vs * (1.0f / HID) + 1e-5f);
            const float h = d * inv * lng + lnb;
            sff[r * FPAD + lane] = h;                  // h overwrites ff1 row
            float sc = h * gw;
#pragma unroll
            for (int m = 32; m; m >>= 1) sc += __shfl_xor(sc, m);
            if (lane == 0) sscore[r] = sc + gate_b[0];
        }
    }
    __syncthreads();

    // ---- rank ids by score desc (tie -> lower id) -------------------------
    if (t < VOC) {
        const float sv = sscore[t];
        int r = 0;
        for (int u = 0; u < VOC; ++u) {
            const float su = sscore[u];
            if (su > sv || (su == sv && u < t)) ++r;
        }
        sorder[r] = t;
    }
    __syncthreads();

    // ---- greedy top-8 multiset via register count-passes (exp. 1 pass) ----
    for (int pos = 0; pos < VOC; ++pos) {
        if (t == 0) s_u = sorder[pos];
        __syncthreads();
        const int u = s_u;
        int c = (a.x == u) + (a.y == u) + (a.z == u) + (a.w == u);
#pragma unroll
        for (int m = 32; m; m >>= 1) c += __shfl_xor(c, m);
        if (lane == 0) scw[wave] = c;
        __syncthreads();
        if (t == 0) {
            int tot = 0;
            for (int w = 0; w < NW; ++w) tot += scw[w];
            int take = tot < s_rem ? tot : s_rem;
            for (int k = 0; k < take; ++k) svids[s_nv++] = u;
            s_rem -= take;
        }
        __syncthreads();
        if (s_rem == 0) break;
    }

    // ---- q row of last token ----------------------------------------------
    const int vlast = shvlast;
    if (t < HID) {
        float qa = q_b[t];
        for (int k = 0; k < HID; ++k)
            qa = fmaf(sff[vlast * FPAD + k], q_w[k * HID + t], qa);
        sqv[t] = qa;
    }
    __syncthreads();

    // ---- attention logits: 8 lanes per slot, 3-step shfl reduce -----------
    if (t < VOC) {
        const int k = t >> 3, e = t & 7;
        const float* hr = &sff[svids[k] * FPAD];
        float p = 0.0f;
#pragma unroll
        for (int m = 0; m < 8; ++m)
            p = fmaf(hr[e + 8 * m], sqv[e + 8 * m], p);
        p += __shfl_xor(p, 1);
        p += __shfl_xor(p, 2);
        p += __shfl_xor(p, 4);
        if (e == 0) sla[k] = p * 0.125f;               // 1/sqrt(64)
    }
    __syncthreads();

    // ---- softmax + entropy gate; publish entropy via flag handshake -------
    if (t == 0) {
        float m = -1e30f;
        for (int k = 0; k < NSLOT; ++k) m = fmaxf(m, sla[k]);
        float e[NSLOT], s = 0.0f;
        for (int k = 0; k < NSLOT; ++k) { e[k] = expf(sla[k] - m); s += e[k]; }
        const float invs = 1.0f / s;
        float ent = 0.0f;
        for (int k = 0; k < NSLOT; ++k) {
            const float av = e[k] * invs;
            ent -= av * logf(av + 1e-9f);
        }
        const float high = (ent > 1.5f) ? 1.0f : 0.0f;
        for (int k = 0; k < NSLOT; ++k)
            seff[k] = (1.0f - high) * (e[k] * invs) + high * (1.0f / NSLOT);
        __hip_atomic_store(&entw[b], ent, __ATOMIC_RELAXED,
                           __HIP_MEMORY_SCOPE_AGENT);
        __hip_atomic_store(&flags[b], MAGIC, __ATOMIC_RELEASE,
                           __HIP_MEMORY_SCOPE_AGENT);
    }
    __syncthreads();

    // ---- ctx then logits --------------------------------------------------
    if (t < HID) {
        float cx = 0.0f;
#pragma unroll
        for (int k = 0; k < NSLOT; ++k)
            cx = fmaf(seff[k], sff[svids[k] * FPAD + t], cx);
        sctx[t] = cx;
    }
    __syncthreads();
    if (t < VOC) {
        float o = out_b[t];
        for (int i = 0; i < HID; ++i)
            o = fmaf(sctx[i], out_w[i * VOC + t], o);
        out[(size_t)b * VOC + t] = o;
    }
}

extern "C" void kernel_launch(void* const* d_in, const int* in_sizes, int n_in,
                              void* d_out, int out_size, void* d_ws, size_t ws_size,
                              hipStream_t stream) {
    const int*   seq    = (const int*)  d_in[0];
    const float* embed  = (const float*)d_in[1];
    const float* w1     = (const float*)d_in[2];
    const float* b1     = (const float*)d_in[3];
    const float* w2     = (const float*)d_in[4];
    const float* b2     = (const float*)d_in[5];
    const float* ln_g   = (const float*)d_in[6];
    const float* ln_b   = (const float*)d_in[7];
    const float* gate_w = (const float*)d_in[8];
    const float* gate_b = (const float*)d_in[9];
    const float* q_w    = (const float*)d_in[10];
    const float* q_b    = (const float*)d_in[11];
    const float* out_w  = (const float*)d_in[12];
    const float* out_b  = (const float*)d_in[13];
    float* out = (float*)d_out;

    float* entw  = (float*)d_ws;            // 256 floats
    int*   flags = (int*)d_ws + NB;         // 256 ints

    fused_kernel<<<NB + 1, NT, 0, stream>>>(seq, embed, w1, b1, w2, b2,
                                            ln_g, ln_b, gate_w, gate_b,
                                            q_w, q_b, out_w, out_b,
                                            out, entw, flags);
}